// Round 2
// baseline (681.451 us; speedup 1.0000x reference)
//
#include <hip/hip_runtime.h>
#include <math.h>

#define BATCH 2048
#define SEQ   128
#define HID   512
#define OUTT  24
#define RPB   8               // batch rows per block; hi/lo packed into MFMA M=16
#define NBLK  (BATCH/RPB)     // 256 blocks -> one per CU
#define TPB   512             // 8 waves
#define NTW   4               // n-tiles per wave (8 waves x 4 = 32 n-tiles = 512 cols)
#define KTN   (HID/32)        // 16 k-tiles
#define HOLD_KT 6             // k-tiles held in regs (96 VGPR/lane, total ~232 < 256)
#define LDSB_KT 4             // k-tiles staged in LDS (128 KB)
#define STR_KT  (KTN - HOLD_KT - LDSB_KT)   // 6 streamed from L2 per step
#define LDSB_BASE HOLD_KT                   // kt 6..9 in LDS
#define STR_BASE  (HOLD_KT + LDSB_KT)       // kt 10..15 streamed

typedef _Float16 half8 __attribute__((ext_vector_type(8)));
typedef float   floatx4 __attribute__((ext_vector_type(4)));

// fast tanh: 1 - 2/(e^{2x}+1), e^{2x} = 2^(x*2/ln2). Saturates correctly.
__device__ __forceinline__ float ftanh(float x) {
    float e = __builtin_amdgcn_exp2f(x * 2.885390081777927f);
    float r = __builtin_amdgcn_rcpf(e + 1.0f);
    return fmaf(-2.0f, r, 1.0f);
}

// Pack W[j][k] (row-major HIDxHID fp32) into per-lane MFMA B-fragment layout,
// fp16: frag[(kt*32+nt)*64 + lane][8]; lane holds
// B[k = kt*32 + (lane>>4)*8 + jj][n = nt*16 + (lane&15)] = W[n][k].
__global__ __launch_bounds__(256) void pack_wfrag(const float* __restrict__ W,
                                                  _Float16* __restrict__ Bw)
{
    int id   = blockIdx.x * 256 + threadIdx.x;
    int lane = id & 63;
    int nt   = (id >> 6) & 31;
    int kt   = id >> 11;
    int n  = nt * 16 + (lane & 15);
    int k0 = kt * 32 + (lane >> 4) * 8;
    const float* src = W + (size_t)n * HID + k0;
    half8 v;
    #pragma unroll
    for (int j = 0; j < 8; j++) v[j] = (_Float16)src[j];
    *(half8*)&Bw[(size_t)id * 8] = v;
}

// Swizzled A layout: el(m,k) = (k>>5)*512 + G*128 + ((m^G)<<3) + (k&7), G=(k>>3)&3.
// m in 0..15: m<8 -> hi(fp16) of batch row m; m>=8 -> lo residual of batch row m-8.
// Reader lane (q,c), k-tile kt: contiguous aligned 16 B at kt*512 + q*128 + ((c^q)<<3).
__global__ __launch_bounds__(TPB, 2) void rnn_persist(
    const float* __restrict__ x,
    const _Float16* __restrict__ BwE,
    const _Float16* __restrict__ BwD,
    const float* __restrict__ encWih, const float* __restrict__ encBih,
    const float* __restrict__ encBhh,
    const float* __restrict__ decWih, const float* __restrict__ decBih,
    const float* __restrict__ decBhh,
    const float* __restrict__ fcW, const float* __restrict__ fcB,
    float* __restrict__ out)
{
    __shared__ _Float16 A[KTN * 512];           // 16 KB, single-buffered h state
    __shared__ _Float16 BwL[LDSB_KT * 16384];   // 128 KB LDS-resident weight k-tiles
    __shared__ float    xs[RPB][SEQ];           // 4 KB
    __shared__ float    dec_in_s[RPB];

    const int tid  = threadIdx.x;
    const int lane = tid & 63;
    const int wv   = tid >> 6;
    const int row0 = blockIdx.x * RPB;
    const int c    = lane & 15;
    const int q    = lane >> 4;
    const int qh   = q & 1;        // batch-row group within the duplicated halves
    const int lohalf = q >> 1;     // 0: lanes hold/write hi rows, 1: lo rows
    const int mB   = qh * 4;

    // epilogue constants per owned n
    float eWi[NTW], eBb[NTW], dWi[NTW], dBb[NTW];
    #pragma unroll
    for (int i = 0; i < NTW; i++) {
        int n = (wv * NTW + i) * 16 + c;
        eWi[i] = encWih[n]; eBb[i] = encBih[n] + encBhh[n];
        dWi[i] = decWih[n]; dBb[i] = decBih[n] + decBhh[n];
    }
    const float fcb0 = fcB[0];

    // preload x block-slice into LDS (coalesced float4): 8 rows x 128
    {
        const float4* xg = (const float4*)(x + (size_t)row0 * SEQ);
        if (tid < RPB * SEQ / 4) ((float4*)xs)[tid] = xg[tid];
    }

    // h0 = 0 (hi and lo rows)
    for (int i = tid; i < KTN * 512 / 2; i += TPB) ((int*)A)[i] = 0;

    // stage encoder LDS-resident weight k-tiles (128 KB)
    {
        const float4* src = (const float4*)(BwE + (size_t)LDSB_BASE * 16384);
        float4* dst = (float4*)BwL;
        #pragma unroll
        for (int i = 0; i < LDSB_KT * 16384 / 8 / TPB; i++)
            dst[i * TPB + tid] = src[i * TPB + tid];
    }

    const int    ldsAoff = q * 128 + ((c ^ q) << 3);
    const size_t bbase   = (size_t)(wv * NTW) * 512 + (size_t)lane * 8;
    const int    bbL     = wv * NTW * 512 + lane * 8;

    // ---- load held weight k-tiles into registers (encoder first) ----
    // volatile: cannot be rematerialized -> compiler must keep them resident
    // (VGPR or AGPR -- MFMA reads B from AGPR natively on gfx950).
    half8 wreg[HOLD_KT][NTW];
    #pragma unroll
    for (int kt = 0; kt < HOLD_KT; kt++)
        #pragma unroll
        for (int i = 0; i < NTW; i++)
            wreg[kt][i] = *(const volatile half8*)&BwE[bbase + (size_t)kt * 16384 + i * 512];

    __syncthreads();

    for (int t = 0; t < SEQ + OUTT; t++) {
        const bool enc = (t < SEQ);
        const _Float16* __restrict__ Bw = enc ? BwE : BwD;

        if (t == SEQ) {   // one-time swap to decoder weights (regs + LDS tiles)
            #pragma unroll
            for (int kt = 0; kt < HOLD_KT; kt++)
                #pragma unroll
                for (int i = 0; i < NTW; i++)
                    wreg[kt][i] = *(const volatile half8*)&BwD[bbase + (size_t)kt * 16384 + i * 512];
            const float4* src = (const float4*)(BwD + (size_t)LDSB_BASE * 16384);
            float4* dst = (float4*)BwL;
            #pragma unroll
            for (int i = 0; i < LDSB_KT * 16384 / 8 / TPB; i++)
                dst[i * TPB + tid] = src[i * TPB + tid];
            __syncthreads();
        }

        floatx4 acc[NTW];
        #pragma unroll
        for (int i = 0; i < NTW; i++) acc[i] = (floatx4){0.f, 0.f, 0.f, 0.f};

        // prime streamed-B prefetch (2 k-tiles deep) before held compute
        half8 bcur[NTW], bnxt[NTW];
        #pragma unroll
        for (int i = 0; i < NTW; i++) {
            bcur[i] = *(const half8*)&Bw[bbase + (size_t)STR_BASE * 16384 + i * 512];
            bnxt[i] = *(const half8*)&Bw[bbase + (size_t)(STR_BASE + 1) * 16384 + i * 512];
        }

        // held k-tiles: B from registers, one A-read per kt (hi+lo packed in M)
        #pragma unroll
        for (int kt = 0; kt < HOLD_KT; kt++) {
            half8 a = *(const half8*)&A[kt * 512 + ldsAoff];
            #pragma unroll
            for (int i = 0; i < NTW; i++)
                acc[i] = __builtin_amdgcn_mfma_f32_16x16x32_f16(a, wreg[kt][i], acc[i], 0, 0, 0);
        }

        // LDS-resident k-tiles
        #pragma unroll
        for (int kl = 0; kl < LDSB_KT; kl++) {
            half8 a = *(const half8*)&A[(LDSB_BASE + kl) * 512 + ldsAoff];
            #pragma unroll
            for (int i = 0; i < NTW; i++) {
                half8 b = *(const half8*)&BwL[kl * 16384 + bbL + i * 512];
                acc[i] = __builtin_amdgcn_mfma_f32_16x16x32_f16(a, b, acc[i], 0, 0, 0);
            }
        }

        // streamed k-tiles with rolling 2-deep prefetch
        #pragma unroll
        for (int s = 0; s < STR_KT; s++) {
            const int kt = STR_BASE + s;
            half8 bpre[NTW];
            if (s + 2 < STR_KT) {
                #pragma unroll
                for (int i = 0; i < NTW; i++)
                    bpre[i] = *(const half8*)&Bw[bbase + (size_t)(kt + 2) * 16384 + i * 512];
            }
            half8 a = *(const half8*)&A[kt * 512 + ldsAoff];
            #pragma unroll
            for (int i = 0; i < NTW; i++)
                acc[i] = __builtin_amdgcn_mfma_f32_16x16x32_f16(a, bcur[i], acc[i], 0, 0, 0);
            #pragma unroll
            for (int i = 0; i < NTW; i++) {
                bcur[i] = bnxt[i];
                if (s + 2 < STR_KT) bnxt[i] = bpre[i];
            }
        }

        __syncthreads();   // all reads of A (h_t) complete before overwrite

        // ---- epilogue: combine hi/lo halves, tanh, write packed A in place ----
        float inp[4];
        if (enc) {
            #pragma unroll
            for (int r = 0; r < 4; r++) inp[r] = xs[mB + r][t];
        } else if (t == SEQ) {
            #pragma unroll
            for (int r = 0; r < 4; r++) inp[r] = xs[mB + r][SEQ - 1];
        } else {
            #pragma unroll
            for (int r = 0; r < 4; r++) inp[r] = dec_in_s[mB + r];
        }

        #pragma unroll
        for (int i = 0; i < NTW; i++) {
            int n = (wv * NTW + i) * 16 + c;   // this n is next step's k
            int G = (n >> 3) & 3;
            int base = (n >> 5) * 512 + G * 128 + (n & 7);
            float wi = enc ? eWi[i] : dWi[i];
            float bb = enc ? eBb[i] : dBb[i];
            #pragma unroll
            for (int r = 0; r < 4; r++) {
                // D rows 0-7 (lanes 0-31) = hi contribution, rows 8-15 (lanes 32-63) = lo
                float sum = acc[i][r] + __shfl_xor(acc[i][r], 32, 64);
                float v = ftanh(sum + inp[r] * wi + bb);
                _Float16 hh = (_Float16)v;
                _Float16 rs = (_Float16)(v - (float)hh);
                int mw = mB + r + (lohalf << 3);       // hi row or lo row
                A[base + ((mw ^ G) << 3)] = lohalf ? rs : hh;
            }
        }
        __syncthreads();   // A (h_{t+1}) complete

        if (!enc) {
            // FC: wave wv reduces row wv (8 waves, 8 rows)
            const int m = wv;
            float sfc = 0.f;
            #pragma unroll
            for (int ii = 0; ii < HID / 64; ii++) {
                int k = ii * 64 + lane;
                int G = (k >> 3) & 3;
                int a0 = (k >> 5) * 512 + G * 128 + (k & 7);
                float hv = (float)A[a0 + ((m ^ G) << 3)]
                         + (float)A[a0 + (((m + 8) ^ G) << 3)];
                sfc = fmaf(hv, fcW[k], sfc);
            }
            #pragma unroll
            for (int off = 32; off > 0; off >>= 1)
                sfc += __shfl_down(sfc, off, 64);
            if (lane == 0) {
                float o = sfc + fcb0;
                dec_in_s[m] = o;
                out[(size_t)(row0 + m) * OUTT + (t - SEQ)] = o;
            }
            __syncthreads();
        }
    }
}

extern "C" void kernel_launch(void* const* d_in, const int* in_sizes, int n_in,
                              void* d_out, int out_size, void* d_ws, size_t ws_size,
                              hipStream_t stream)
{
    const float* x        = (const float*)d_in[0];
    const float* enc_Wih  = (const float*)d_in[1];
    const float* enc_Whh  = (const float*)d_in[2];
    const float* enc_bih  = (const float*)d_in[3];
    const float* enc_bhh  = (const float*)d_in[4];
    const float* dec_Wih  = (const float*)d_in[5];
    const float* dec_Whh  = (const float*)d_in[6];
    const float* dec_bih  = (const float*)d_in[7];
    const float* dec_bhh  = (const float*)d_in[8];
    const float* fc_W     = (const float*)d_in[9];
    const float* fc_b     = (const float*)d_in[10];
    float* out = (float*)d_out;

    const size_t wfrag = (size_t)HID * HID;
    _Float16* BwE = (_Float16*)d_ws;
    _Float16* BwD = BwE + wfrag;

    pack_wfrag<<<HID * HID / (256 * 8), 256, 0, stream>>>(enc_Whh, BwE);
    pack_wfrag<<<HID * HID / (256 * 8), 256, 0, stream>>>(dec_Whh, BwD);

    rnn_persist<<<NBLK, TPB, 0, stream>>>(
        x, BwE, BwD,
        enc_Wih, enc_bih, enc_bhh,
        dec_Wih, dec_bih, dec_bhh,
        fc_W, fc_b, out);
}

// Round 3
// 676.220 us; speedup vs baseline: 1.0077x; 1.0077x over previous
//
#include <hip/hip_runtime.h>
#include <math.h>

#define BATCH 2048
#define SEQ   128
#define HID   512
#define OUTT  24
#define RPB   8               // batch rows per block; hi/lo packed into MFMA M=16
#define NBLK  (BATCH/RPB)     // 256 blocks -> one per CU
#define TPB   512             // 8 waves
#define NTW   4               // n-tiles per wave (8 waves x 4 = 32 n-tiles = 512 cols)
#define KTN   (HID/32)        // 16 k-tiles
#define HOLD_KT 6             // k-tiles held in AGPRs (96 AGPR/lane, forced via asm "a")
#define LDSB_KT 4             // k-tiles staged in LDS (128 KB)
#define STR_KT  (KTN - HOLD_KT - LDSB_KT)   // 6 streamed from L2 per step
#define LDSB_BASE HOLD_KT                   // kt 6..9 in LDS
#define STR_BASE  (HOLD_KT + LDSB_KT)       // kt 10..15 streamed

typedef _Float16 half8 __attribute__((ext_vector_type(8)));
typedef float   floatx4 __attribute__((ext_vector_type(4)));

// MFMA with B forced into an AGPR quad: residency is a constraint, not a
// register-allocator heuristic. gfx950 MFMA reads B from AGPR natively.
__device__ __forceinline__ void mfma_ha(floatx4& c, half8 a, half8 b) {
    asm("v_mfma_f32_16x16x32_f16 %0, %1, %2, %0" : "+v"(c) : "v"(a), "a"(b));
}
// Plain-VGPR form for streamed / LDS-resident B.
__device__ __forceinline__ void mfma_hv(floatx4& c, half8 a, half8 b) {
    c = __builtin_amdgcn_mfma_f32_16x16x32_f16(a, b, c, 0, 0, 0);
}

// fast tanh: 1 - 2/(e^{2x}+1), e^{2x} = 2^(x*2/ln2). Saturates correctly.
__device__ __forceinline__ float ftanh(float x) {
    float e = __builtin_amdgcn_exp2f(x * 2.885390081777927f);
    float r = __builtin_amdgcn_rcpf(e + 1.0f);
    return fmaf(-2.0f, r, 1.0f);
}

// Pack W[j][k] (row-major HIDxHID fp32) into per-lane MFMA B-fragment layout,
// fp16: frag[(kt*32+nt)*64 + lane][8]; lane holds
// B[k = kt*32 + (lane>>4)*8 + jj][n = nt*16 + (lane&15)] = W[n][k].
__global__ __launch_bounds__(256) void pack_wfrag(const float* __restrict__ W,
                                                  _Float16* __restrict__ Bw)
{
    int id   = blockIdx.x * 256 + threadIdx.x;
    int lane = id & 63;
    int nt   = (id >> 6) & 31;
    int kt   = id >> 11;
    int n  = nt * 16 + (lane & 15);
    int k0 = kt * 32 + (lane >> 4) * 8;
    const float* src = W + (size_t)n * HID + k0;
    half8 v;
    #pragma unroll
    for (int j = 0; j < 8; j++) v[j] = (_Float16)src[j];
    *(half8*)&Bw[(size_t)id * 8] = v;
}

// Swizzled A layout: el(m,k) = (k>>5)*512 + G*128 + ((m^G)<<3) + (k&7), G=(k>>3)&3.
// m in 0..15: m<8 -> hi(fp16) of batch row m; m>=8 -> lo residual of batch row m-8.
// Reader lane (q,c), k-tile kt: contiguous aligned 16 B at kt*512 + q*128 + ((c^q)<<3).
__global__ __launch_bounds__(TPB, 2) void rnn_persist(
    const float* __restrict__ x,
    const _Float16* __restrict__ BwE,
    const _Float16* __restrict__ BwD,
    const float* __restrict__ encWih, const float* __restrict__ encBih,
    const float* __restrict__ encBhh,
    const float* __restrict__ decWih, const float* __restrict__ decBih,
    const float* __restrict__ decBhh,
    const float* __restrict__ fcW, const float* __restrict__ fcB,
    float* __restrict__ out)
{
    __shared__ _Float16 A[KTN * 512];           // 16 KB, single-buffered h state
    __shared__ _Float16 BwL[LDSB_KT * 16384];   // 128 KB LDS-resident weight k-tiles
    __shared__ float    xs[RPB][SEQ];           // 4 KB
    __shared__ float    dec_in_s[RPB];

    const int tid  = threadIdx.x;
    const int lane = tid & 63;
    const int wv   = tid >> 6;
    const int row0 = blockIdx.x * RPB;
    const int c    = lane & 15;
    const int q    = lane >> 4;
    const int qh   = q & 1;        // batch-row group within the duplicated halves
    const int lohalf = q >> 1;     // 0: lanes hold/write hi rows, 1: lo rows
    const int mB   = qh * 4;

    // epilogue constants per owned n
    float eWi[NTW], eBb[NTW], dWi[NTW], dBb[NTW];
    #pragma unroll
    for (int i = 0; i < NTW; i++) {
        int n = (wv * NTW + i) * 16 + c;
        eWi[i] = encWih[n]; eBb[i] = encBih[n] + encBhh[n];
        dWi[i] = decWih[n]; dBb[i] = decBih[n] + decBhh[n];
    }
    const float fcb0 = fcB[0];

    // preload x block-slice into LDS (coalesced float4): 8 rows x 128
    {
        const float4* xg = (const float4*)(x + (size_t)row0 * SEQ);
        if (tid < RPB * SEQ / 4) ((float4*)xs)[tid] = xg[tid];
    }

    // h0 = 0 (hi and lo rows)
    for (int i = tid; i < KTN * 512 / 2; i += TPB) ((int*)A)[i] = 0;

    // stage encoder LDS-resident weight k-tiles (128 KB)
    {
        const float4* src = (const float4*)(BwE + (size_t)LDSB_BASE * 16384);
        float4* dst = (float4*)BwL;
        #pragma unroll
        for (int i = 0; i < LDSB_KT * 16384 / 8 / TPB; i++)
            dst[i * TPB + tid] = src[i * TPB + tid];
    }

    const int    ldsAoff = q * 128 + ((c ^ q) << 3);
    const size_t bbase   = (size_t)(wv * NTW) * 512 + (size_t)lane * 8;
    const int    bbL     = wv * NTW * 512 + lane * 8;

    // ---- load held weight k-tiles (encoder first); used only as asm "a"
    // operands, so the allocator must keep them in AGPRs: no scratch possible.
    half8 wreg[HOLD_KT][NTW];
    #pragma unroll
    for (int kt = 0; kt < HOLD_KT; kt++)
        #pragma unroll
        for (int i = 0; i < NTW; i++)
            wreg[kt][i] = *(const half8*)&BwE[bbase + (size_t)kt * 16384 + i * 512];

    __syncthreads();

    for (int t = 0; t < SEQ + OUTT; t++) {
        const bool enc = (t < SEQ);
        const _Float16* __restrict__ Bw = enc ? BwE : BwD;

        if (t == SEQ) {   // one-time swap to decoder weights (regs + LDS tiles)
            #pragma unroll
            for (int kt = 0; kt < HOLD_KT; kt++)
                #pragma unroll
                for (int i = 0; i < NTW; i++)
                    wreg[kt][i] = *(const half8*)&BwD[bbase + (size_t)kt * 16384 + i * 512];
            const float4* src = (const float4*)(BwD + (size_t)LDSB_BASE * 16384);
            float4* dst = (float4*)BwL;
            #pragma unroll
            for (int i = 0; i < LDSB_KT * 16384 / 8 / TPB; i++)
                dst[i * TPB + tid] = src[i * TPB + tid];
            __syncthreads();
        }

        floatx4 acc[NTW];
        #pragma unroll
        for (int i = 0; i < NTW; i++) acc[i] = (floatx4){0.f, 0.f, 0.f, 0.f};

        // prime streamed-B prefetch (2 k-tiles deep) before held compute
        half8 bcur[NTW], bnxt[NTW];
        #pragma unroll
        for (int i = 0; i < NTW; i++) {
            bcur[i] = *(const half8*)&Bw[bbase + (size_t)STR_BASE * 16384 + i * 512];
            bnxt[i] = *(const half8*)&Bw[bbase + (size_t)(STR_BASE + 1) * 16384 + i * 512];
        }

        // held k-tiles: B from AGPRs, one A-read per kt (hi+lo packed in M)
        #pragma unroll
        for (int kt = 0; kt < HOLD_KT; kt++) {
            half8 a = *(const half8*)&A[kt * 512 + ldsAoff];
            #pragma unroll
            for (int i = 0; i < NTW; i++)
                mfma_ha(acc[i], a, wreg[kt][i]);
        }

        // LDS-resident k-tiles
        #pragma unroll
        for (int kl = 0; kl < LDSB_KT; kl++) {
            half8 a = *(const half8*)&A[(LDSB_BASE + kl) * 512 + ldsAoff];
            #pragma unroll
            for (int i = 0; i < NTW; i++) {
                half8 b = *(const half8*)&BwL[kl * 16384 + bbL + i * 512];
                mfma_hv(acc[i], a, b);
            }
        }

        // streamed k-tiles with rolling 2-deep prefetch
        #pragma unroll
        for (int s = 0; s < STR_KT; s++) {
            const int kt = STR_BASE + s;
            half8 bpre[NTW];
            if (s + 2 < STR_KT) {
                #pragma unroll
                for (int i = 0; i < NTW; i++)
                    bpre[i] = *(const half8*)&Bw[bbase + (size_t)(kt + 2) * 16384 + i * 512];
            }
            half8 a = *(const half8*)&A[kt * 512 + ldsAoff];
            #pragma unroll
            for (int i = 0; i < NTW; i++)
                mfma_hv(acc[i], a, bcur[i]);
            #pragma unroll
            for (int i = 0; i < NTW; i++) {
                bcur[i] = bnxt[i];
                if (s + 2 < STR_KT) bnxt[i] = bpre[i];
            }
        }

        __syncthreads();   // all reads of A (h_t) complete before overwrite

        // ---- epilogue: combine hi/lo halves, tanh, write packed A in place ----
        float inp[4];
        if (enc) {
            #pragma unroll
            for (int r = 0; r < 4; r++) inp[r] = xs[mB + r][t];
        } else if (t == SEQ) {
            #pragma unroll
            for (int r = 0; r < 4; r++) inp[r] = xs[mB + r][SEQ - 1];
        } else {
            #pragma unroll
            for (int r = 0; r < 4; r++) inp[r] = dec_in_s[mB + r];
        }

        #pragma unroll
        for (int i = 0; i < NTW; i++) {
            int n = (wv * NTW + i) * 16 + c;   // this n is next step's k
            int G = (n >> 3) & 3;
            int base = (n >> 5) * 512 + G * 128 + (n & 7);
            float wi = enc ? eWi[i] : dWi[i];
            float bb = enc ? eBb[i] : dBb[i];
            #pragma unroll
            for (int r = 0; r < 4; r++) {
                // D rows 0-7 (lanes 0-31) = hi contribution, rows 8-15 (lanes 32-63) = lo
                float sum = acc[i][r] + __shfl_xor(acc[i][r], 32, 64);
                float v = ftanh(sum + inp[r] * wi + bb);
                _Float16 hh = (_Float16)v;
                _Float16 rs = (_Float16)(v - (float)hh);
                int mw = mB + r + (lohalf << 3);       // hi row or lo row
                A[base + ((mw ^ G) << 3)] = lohalf ? rs : hh;
            }
        }
        __syncthreads();   // A (h_{t+1}) complete

        if (!enc) {
            // FC: wave wv reduces row wv (8 waves, 8 rows)
            const int m = wv;
            float sfc = 0.f;
            #pragma unroll
            for (int ii = 0; ii < HID / 64; ii++) {
                int k = ii * 64 + lane;
                int G = (k >> 3) & 3;
                int a0 = (k >> 5) * 512 + G * 128 + (k & 7);
                float hv = (float)A[a0 + ((m ^ G) << 3)]
                         + (float)A[a0 + (((m + 8) ^ G) << 3)];
                sfc = fmaf(hv, fcW[k], sfc);
            }
            #pragma unroll
            for (int off = 32; off > 0; off >>= 1)
                sfc += __shfl_down(sfc, off, 64);
            if (lane == 0) {
                float o = sfc + fcb0;
                dec_in_s[m] = o;
                out[(size_t)(row0 + m) * OUTT + (t - SEQ)] = o;
            }
            __syncthreads();
        }
    }
}

extern "C" void kernel_launch(void* const* d_in, const int* in_sizes, int n_in,
                              void* d_out, int out_size, void* d_ws, size_t ws_size,
                              hipStream_t stream)
{
    const float* x        = (const float*)d_in[0];
    const float* enc_Wih  = (const float*)d_in[1];
    const float* enc_Whh  = (const float*)d_in[2];
    const float* enc_bih  = (const float*)d_in[3];
    const float* enc_bhh  = (const float*)d_in[4];
    const float* dec_Wih  = (const float*)d_in[5];
    const float* dec_Whh  = (const float*)d_in[6];
    const float* dec_bih  = (const float*)d_in[7];
    const float* dec_bhh  = (const float*)d_in[8];
    const float* fc_W     = (const float*)d_in[9];
    const float* fc_b     = (const float*)d_in[10];
    float* out = (float*)d_out;

    const size_t wfrag = (size_t)HID * HID;
    _Float16* BwE = (_Float16*)d_ws;
    _Float16* BwD = BwE + wfrag;

    pack_wfrag<<<HID * HID / (256 * 8), 256, 0, stream>>>(enc_Whh, BwE);
    pack_wfrag<<<HID * HID / (256 * 8), 256, 0, stream>>>(dec_Whh, BwD);

    rnn_persist<<<NBLK, TPB, 0, stream>>>(
        x, BwE, BwD,
        enc_Wih, enc_bih, enc_bhh,
        dec_Wih, dec_bih, dec_bhh,
        fc_W, fc_b, out);
}

// Round 4
// 618.243 us; speedup vs baseline: 1.1022x; 1.0938x over previous
//
#include <hip/hip_runtime.h>
#include <math.h>

#define BATCH 2048
#define SEQ   128
#define HID   512
#define OUTT  24
#define RPB   8               // batch rows per block; hi/lo packed into MFMA M=16
#define NBLK  (BATCH/RPB)     // 256 blocks -> one per CU
#define TPB   1024            // 16 waves = 4/SIMD (was 8 = 2/SIMD)
#define NTW   2               // n-tiles per wave (16 waves x 2 = 32 n-tiles = 512 cols)
#define KTN   (HID/32)        // 16 k-tiles
#define HOLD_KT 6             // k-tiles held in regs (48 VGPR/lane at NTW=2)
#define LDSB_KT 4             // k-tiles staged in LDS (128 KB)
#define STR_KT  (KTN - HOLD_KT - LDSB_KT)   // 6 streamed from L2 per step
#define LDSB_BASE HOLD_KT                   // kt 6..9 in LDS
#define STR_BASE  (HOLD_KT + LDSB_KT)       // kt 10..15 streamed

typedef _Float16 half8 __attribute__((ext_vector_type(8)));
typedef float   floatx4 __attribute__((ext_vector_type(4)));

__device__ __forceinline__ void mfma_hv(floatx4& c, half8 a, half8 b) {
    c = __builtin_amdgcn_mfma_f32_16x16x32_f16(a, b, c, 0, 0, 0);
}

// fast tanh: 1 - 2/(e^{2x}+1), e^{2x} = 2^(x*2/ln2). Saturates correctly.
__device__ __forceinline__ float ftanh(float x) {
    float e = __builtin_amdgcn_exp2f(x * 2.885390081777927f);
    float r = __builtin_amdgcn_rcpf(e + 1.0f);
    return fmaf(-2.0f, r, 1.0f);
}

// Pack W[j][k] (row-major HIDxHID fp32) into per-lane MFMA B-fragment layout,
// fp16: frag[(kt*32+nt)*64 + lane][8]; lane holds
// B[k = kt*32 + (lane>>4)*8 + jj][n = nt*16 + (lane&15)] = W[n][k].
__global__ __launch_bounds__(256) void pack_wfrag(const float* __restrict__ W,
                                                  _Float16* __restrict__ Bw)
{
    int id   = blockIdx.x * 256 + threadIdx.x;
    int lane = id & 63;
    int nt   = (id >> 6) & 31;
    int kt   = id >> 11;
    int n  = nt * 16 + (lane & 15);
    int k0 = kt * 32 + (lane >> 4) * 8;
    const float* src = W + (size_t)n * HID + k0;
    half8 v;
    #pragma unroll
    for (int j = 0; j < 8; j++) v[j] = (_Float16)src[j];
    *(half8*)&Bw[(size_t)id * 8] = v;
}

// Swizzled A layout: el(m,k) = (k>>5)*512 + G*128 + ((m^G)<<3) + (k&7), G=(k>>3)&3.
// m in 0..15: m<8 -> hi(fp16) of batch row m; m>=8 -> lo residual of batch row m-8.
// Reader lane (q,c), k-tile kt: contiguous aligned 16 B at kt*512 + q*128 + ((c^q)<<3).
__global__ __launch_bounds__(TPB, 4) void rnn_persist(
    const float* __restrict__ x,
    const _Float16* __restrict__ BwE,
    const _Float16* __restrict__ BwD,
    const float* __restrict__ encWih, const float* __restrict__ encBih,
    const float* __restrict__ encBhh,
    const float* __restrict__ decWih, const float* __restrict__ decBih,
    const float* __restrict__ decBhh,
    const float* __restrict__ fcW, const float* __restrict__ fcB,
    float* __restrict__ out)
{
    __shared__ _Float16 A[KTN * 512];           // 16 KB, single-buffered h state
    __shared__ _Float16 BwL[LDSB_KT * 16384];   // 128 KB LDS-resident weight k-tiles
    __shared__ float    xs[RPB][SEQ];           // 4 KB
    __shared__ float    dec_in_s[RPB];

    const int tid  = threadIdx.x;
    const int lane = tid & 63;
    const int wv   = tid >> 6;                  // 0..15
    const int row0 = blockIdx.x * RPB;
    const int c    = lane & 15;
    const int q    = lane >> 4;
    const int qh   = q & 1;        // batch-row group within the duplicated halves
    const int lohalf = q >> 1;     // 0: lanes hold/write hi rows, 1: lo rows
    const int mB   = qh * 4;

    const float fcb0 = fcB[0];

    // preload x block-slice into LDS (coalesced float4): 8 rows x 128
    {
        const float4* xg = (const float4*)(x + (size_t)row0 * SEQ);
        if (tid < RPB * SEQ / 4) ((float4*)xs)[tid] = xg[tid];
    }

    // h0 = 0 (hi and lo rows)
    for (int i = tid; i < KTN * 512 / 2; i += TPB) ((int*)A)[i] = 0;

    // stage encoder LDS-resident weight k-tiles (128 KB)
    {
        const float4* src = (const float4*)(BwE + (size_t)LDSB_BASE * 16384);
        float4* dst = (float4*)BwL;
        #pragma unroll
        for (int i = 0; i < LDSB_KT * 16384 / 8 / TPB; i++)
            dst[i * TPB + tid] = src[i * TPB + tid];
    }

    const int    ldsAoff = q * 128 + ((c ^ q) << 3);
    const size_t bbase   = (size_t)(wv * NTW) * 512 + (size_t)lane * 8;
    const int    bbL     = wv * NTW * 512 + lane * 8;

    // ---- load held weight k-tiles into registers (encoder first) ----
    half8 wreg[HOLD_KT][NTW];
    #pragma unroll
    for (int kt = 0; kt < HOLD_KT; kt++)
        #pragma unroll
        for (int i = 0; i < NTW; i++)
            wreg[kt][i] = *(const half8*)&BwE[bbase + (size_t)kt * 16384 + i * 512];

    __syncthreads();

    for (int t = 0; t < SEQ + OUTT; t++) {
        const bool enc = (t < SEQ);
        const _Float16* __restrict__ Bw = enc ? BwE : BwD;

        if (t == SEQ) {   // one-time swap to decoder weights (regs + LDS tiles)
            #pragma unroll
            for (int kt = 0; kt < HOLD_KT; kt++)
                #pragma unroll
                for (int i = 0; i < NTW; i++)
                    wreg[kt][i] = *(const half8*)&BwD[bbase + (size_t)kt * 16384 + i * 512];
            const float4* src = (const float4*)(BwD + (size_t)LDSB_BASE * 16384);
            float4* dst = (float4*)BwL;
            #pragma unroll
            for (int i = 0; i < LDSB_KT * 16384 / 8 / TPB; i++)
                dst[i * TPB + tid] = src[i * TPB + tid];
            __syncthreads();
        }

        floatx4 acc[NTW];
        #pragma unroll
        for (int i = 0; i < NTW; i++) acc[i] = (floatx4){0.f, 0.f, 0.f, 0.f};

        // prime streamed-B prefetch (2 k-tiles deep) before held compute
        half8 bcur[NTW], bnxt[NTW];
        #pragma unroll
        for (int i = 0; i < NTW; i++) {
            bcur[i] = *(const half8*)&Bw[bbase + (size_t)STR_BASE * 16384 + i * 512];
            bnxt[i] = *(const half8*)&Bw[bbase + (size_t)(STR_BASE + 1) * 16384 + i * 512];
        }

        // held k-tiles: B from registers, one A-read per kt (hi+lo packed in M)
        #pragma unroll
        for (int kt = 0; kt < HOLD_KT; kt++) {
            half8 a = *(const half8*)&A[kt * 512 + ldsAoff];
            #pragma unroll
            for (int i = 0; i < NTW; i++)
                mfma_hv(acc[i], a, wreg[kt][i]);
        }

        // LDS-resident k-tiles
        #pragma unroll
        for (int kl = 0; kl < LDSB_KT; kl++) {
            half8 a = *(const half8*)&A[(LDSB_BASE + kl) * 512 + ldsAoff];
            #pragma unroll
            for (int i = 0; i < NTW; i++) {
                half8 b = *(const half8*)&BwL[kl * 16384 + bbL + i * 512];
                mfma_hv(acc[i], a, b);
            }
        }

        // streamed k-tiles with rolling 2-deep prefetch
        #pragma unroll
        for (int s = 0; s < STR_KT; s++) {
            const int kt = STR_BASE + s;
            half8 bpre[NTW];
            if (s + 2 < STR_KT) {
                #pragma unroll
                for (int i = 0; i < NTW; i++)
                    bpre[i] = *(const half8*)&Bw[bbase + (size_t)(kt + 2) * 16384 + i * 512];
            }
            half8 a = *(const half8*)&A[kt * 512 + ldsAoff];
            #pragma unroll
            for (int i = 0; i < NTW; i++)
                mfma_hv(acc[i], a, bcur[i]);
            #pragma unroll
            for (int i = 0; i < NTW; i++) {
                bcur[i] = bnxt[i];
                if (s + 2 < STR_KT) bnxt[i] = bpre[i];
            }
        }

        __syncthreads();   // all reads of A (h_t) complete before overwrite

        // ---- epilogue: combine hi/lo halves, tanh, write packed A in place ----
        float inp[4];
        if (enc) {
            #pragma unroll
            for (int r = 0; r < 4; r++) inp[r] = xs[mB + r][t];
        } else if (t == SEQ) {
            #pragma unroll
            for (int r = 0; r < 4; r++) inp[r] = xs[mB + r][SEQ - 1];
        } else {
            #pragma unroll
            for (int r = 0; r < 4; r++) inp[r] = dec_in_s[mB + r];
        }

        // epilogue constants read per step from global (L1-hot, frees VGPRs)
        const float* Wih = enc ? encWih : decWih;
        const float* Bih = enc ? encBih : decBih;
        const float* Bhh = enc ? encBhh : decBhh;

        #pragma unroll
        for (int i = 0; i < NTW; i++) {
            int n = (wv * NTW + i) * 16 + c;   // this n is next step's k
            int G = (n >> 3) & 3;
            int base = (n >> 5) * 512 + G * 128 + (n & 7);
            float wi = Wih[n];
            float bb = Bih[n] + Bhh[n];
            #pragma unroll
            for (int r = 0; r < 4; r++) {
                // D rows 0-7 (lanes 0-31) = hi contribution, rows 8-15 (lanes 32-63) = lo
                float sum = acc[i][r] + __shfl_xor(acc[i][r], 32, 64);
                float v = ftanh(sum + inp[r] * wi + bb);
                _Float16 hh = (_Float16)v;
                _Float16 rs = (_Float16)(v - (float)hh);
                int mw = mB + r + (lohalf << 3);       // hi row or lo row
                A[base + ((mw ^ G) << 3)] = lohalf ? rs : hh;
            }
        }
        __syncthreads();   // A (h_{t+1}) complete

        if (!enc) {
            // FC: waves 0-7 each reduce one row; waves 8-15 idle to the barrier
            if (wv < 8) {
                const int m = wv;
                float sfc = 0.f;
                #pragma unroll
                for (int ii = 0; ii < HID / 64; ii++) {
                    int k = ii * 64 + lane;
                    int G = (k >> 3) & 3;
                    int a0 = (k >> 5) * 512 + G * 128 + (k & 7);
                    float hv = (float)A[a0 + ((m ^ G) << 3)]
                             + (float)A[a0 + (((m + 8) ^ G) << 3)];
                    sfc = fmaf(hv, fcW[k], sfc);
                }
                #pragma unroll
                for (int off = 32; off > 0; off >>= 1)
                    sfc += __shfl_down(sfc, off, 64);
                if (lane == 0) {
                    float o = sfc + fcb0;
                    dec_in_s[m] = o;
                    out[(size_t)(row0 + m) * OUTT + (t - SEQ)] = o;
                }
            }
            __syncthreads();
        }
    }
}

extern "C" void kernel_launch(void* const* d_in, const int* in_sizes, int n_in,
                              void* d_out, int out_size, void* d_ws, size_t ws_size,
                              hipStream_t stream)
{
    const float* x        = (const float*)d_in[0];
    const float* enc_Wih  = (const float*)d_in[1];
    const float* enc_Whh  = (const float*)d_in[2];
    const float* enc_bih  = (const float*)d_in[3];
    const float* enc_bhh  = (const float*)d_in[4];
    const float* dec_Wih  = (const float*)d_in[5];
    const float* dec_Whh  = (const float*)d_in[6];
    const float* dec_bih  = (const float*)d_in[7];
    const float* dec_bhh  = (const float*)d_in[8];
    const float* fc_W     = (const float*)d_in[9];
    const float* fc_b     = (const float*)d_in[10];
    float* out = (float*)d_out;

    const size_t wfrag = (size_t)HID * HID;
    _Float16* BwE = (_Float16*)d_ws;
    _Float16* BwD = BwE + wfrag;

    pack_wfrag<<<HID * HID / (256 * 8), 256, 0, stream>>>(enc_Whh, BwE);
    pack_wfrag<<<HID * HID / (256 * 8), 256, 0, stream>>>(dec_Whh, BwD);

    rnn_persist<<<NBLK, TPB, 0, stream>>>(
        x, BwE, BwD,
        enc_Wih, enc_bih, enc_bhh,
        dec_Wih, dec_bih, dec_bhh,
        fc_W, fc_b, out);
}

// Round 5
// 585.571 us; speedup vs baseline: 1.1637x; 1.0558x over previous
//
#include <hip/hip_runtime.h>
#include <math.h>

#define BATCH 2048
#define SEQ   128
#define HID   512
#define OUTT  24
#define RPB   8               // batch rows per block; hi/lo packed into MFMA M=16
#define NBLK  (BATCH/RPB)     // 256 blocks -> one per CU
#define TPB   1024            // 16 waves = 4/SIMD
#define NTW   2               // n-tiles per wave (16 waves x 2 = 32 n-tiles = 512 cols)
#define KTN   (HID/32)        // 16 k-tiles
#define HOLD_KT 7             // k-tiles held in regs (56 VGPR/lane at NTW=2)
#define LDSB_KT 4             // k-tiles staged in LDS (128 KB)
#define STR_KT  (KTN - HOLD_KT - LDSB_KT)   // 5 streamed from L2 per step
#define LDSB_BASE HOLD_KT                   // kt 7..10 in LDS
#define STR_BASE  (HOLD_KT + LDSB_KT)       // kt 11..15 streamed

typedef _Float16 half8 __attribute__((ext_vector_type(8)));
typedef float   floatx4 __attribute__((ext_vector_type(4)));

__device__ __forceinline__ void mfma_hv(floatx4& c, half8 a, half8 b) {
    c = __builtin_amdgcn_mfma_f32_16x16x32_f16(a, b, c, 0, 0, 0);
}

// fast tanh: 1 - 2/(e^{2x}+1), e^{2x} = 2^(x*2/ln2). Saturates correctly.
__device__ __forceinline__ float ftanh(float x) {
    float e = __builtin_amdgcn_exp2f(x * 2.885390081777927f);
    float r = __builtin_amdgcn_rcpf(e + 1.0f);
    return fmaf(-2.0f, r, 1.0f);
}

// Pack W[j][k] (row-major HIDxHID fp32) into per-lane MFMA B-fragment layout,
// fp16: frag[(kt*32+nt)*64 + lane][8]; lane holds
// B[k = kt*32 + (lane>>4)*8 + jj][n = nt*16 + (lane&15)] = W[n][k].
__global__ __launch_bounds__(256) void pack_wfrag(const float* __restrict__ W,
                                                  _Float16* __restrict__ Bw)
{
    int id   = blockIdx.x * 256 + threadIdx.x;
    int lane = id & 63;
    int nt   = (id >> 6) & 31;
    int kt   = id >> 11;
    int n  = nt * 16 + (lane & 15);
    int k0 = kt * 32 + (lane >> 4) * 8;
    const float* src = W + (size_t)n * HID + k0;
    half8 v;
    #pragma unroll
    for (int j = 0; j < 8; j++) v[j] = (_Float16)src[j];
    *(half8*)&Bw[(size_t)id * 8] = v;
}

// Swizzled A layout: el(m,k) = (k>>5)*512 + G*128 + ((m^G)<<3) + (k&7), G=(k>>3)&3.
// m in 0..15: m<8 -> hi(fp16) of batch row m; m>=8 -> lo residual of batch row m-8.
// Reader lane (q,c), k-tile kt: contiguous aligned 16 B at kt*512 + q*128 + ((c^q)<<3).
// waves_per_eu(4,4): pin BOTH min and max -> allocator budgets 128 VGPR and
// stops chasing 8-wave occupancy it can never get (grid is 1 LDS-bound
// block/CU). This is the anti-spill knob launch_bounds alone doesn't turn.
__global__ __launch_bounds__(TPB)
__attribute__((amdgpu_waves_per_eu(4, 4)))
void rnn_persist(
    const float* __restrict__ x,
    const _Float16* __restrict__ BwE,
    const _Float16* __restrict__ BwD,
    const float* __restrict__ encWih, const float* __restrict__ encBih,
    const float* __restrict__ encBhh,
    const float* __restrict__ decWih, const float* __restrict__ decBih,
    const float* __restrict__ decBhh,
    const float* __restrict__ fcW, const float* __restrict__ fcB,
    float* __restrict__ out)
{
    __shared__ _Float16 A[KTN * 512];           // 16 KB, single-buffered h state
    __shared__ _Float16 BwL[LDSB_KT * 16384];   // 128 KB LDS-resident weight k-tiles
    __shared__ float    xs[RPB][SEQ];           // 4 KB
    __shared__ float    dec_in_s[RPB];

    const int tid  = threadIdx.x;
    const int lane = tid & 63;
    const int wv   = tid >> 6;                  // 0..15
    const int row0 = blockIdx.x * RPB;
    const int c    = lane & 15;
    const int q    = lane >> 4;
    const int qh   = q & 1;        // batch-row group within the duplicated halves
    const int lohalf = q >> 1;     // 0: lanes hold/write hi rows, 1: lo rows
    const int mB   = qh * 4;

    const float fcb0 = fcB[0];

    // epilogue constants per owned n (8 VGPRs -- budget now allows it)
    float eWi[NTW], eBb[NTW], dWi[NTW], dBb[NTW];
    #pragma unroll
    for (int i = 0; i < NTW; i++) {
        int n = (wv * NTW + i) * 16 + c;
        eWi[i] = encWih[n]; eBb[i] = encBih[n] + encBhh[n];
        dWi[i] = decWih[n]; dBb[i] = decBih[n] + decBhh[n];
    }

    // preload x block-slice into LDS (coalesced float4): 8 rows x 128
    {
        const float4* xg = (const float4*)(x + (size_t)row0 * SEQ);
        if (tid < RPB * SEQ / 4) ((float4*)xs)[tid] = xg[tid];
    }

    // h0 = 0 (hi and lo rows)
    for (int i = tid; i < KTN * 512 / 2; i += TPB) ((int*)A)[i] = 0;

    // stage encoder LDS-resident weight k-tiles (128 KB)
    {
        const float4* src = (const float4*)(BwE + (size_t)LDSB_BASE * 16384);
        float4* dst = (float4*)BwL;
        #pragma unroll
        for (int i = 0; i < LDSB_KT * 16384 / 8 / TPB; i++)
            dst[i * TPB + tid] = src[i * TPB + tid];
    }

    const int    ldsAoff = q * 128 + ((c ^ q) << 3);
    const size_t bbase   = (size_t)(wv * NTW) * 512 + (size_t)lane * 8;
    const int    bbL     = wv * NTW * 512 + lane * 8;

    // ---- load held weight k-tiles into registers (encoder first) ----
    half8 wreg[HOLD_KT][NTW];
    #pragma unroll
    for (int kt = 0; kt < HOLD_KT; kt++)
        #pragma unroll
        for (int i = 0; i < NTW; i++)
            wreg[kt][i] = *(const half8*)&BwE[bbase + (size_t)kt * 16384 + i * 512];

    __syncthreads();

    for (int t = 0; t < SEQ + OUTT; t++) {
        const bool enc = (t < SEQ);
        const _Float16* __restrict__ Bw = enc ? BwE : BwD;

        if (t == SEQ) {   // one-time swap to decoder weights (regs + LDS tiles)
            #pragma unroll
            for (int kt = 0; kt < HOLD_KT; kt++)
                #pragma unroll
                for (int i = 0; i < NTW; i++)
                    wreg[kt][i] = *(const half8*)&BwD[bbase + (size_t)kt * 16384 + i * 512];
            const float4* src = (const float4*)(BwD + (size_t)LDSB_BASE * 16384);
            float4* dst = (float4*)BwL;
            #pragma unroll
            for (int i = 0; i < LDSB_KT * 16384 / 8 / TPB; i++)
                dst[i * TPB + tid] = src[i * TPB + tid];
            __syncthreads();
        }

        floatx4 acc[NTW];
        #pragma unroll
        for (int i = 0; i < NTW; i++) acc[i] = (floatx4){0.f, 0.f, 0.f, 0.f};

        // prime streamed-B prefetch (2 k-tiles deep) before held compute
        half8 bcur[NTW], bnxt[NTW];
        #pragma unroll
        for (int i = 0; i < NTW; i++) {
            bcur[i] = *(const half8*)&Bw[bbase + (size_t)STR_BASE * 16384 + i * 512];
            bnxt[i] = *(const half8*)&Bw[bbase + (size_t)(STR_BASE + 1) * 16384 + i * 512];
        }

        // held k-tiles: B from registers, one A-read per kt (hi+lo packed in M)
        #pragma unroll
        for (int kt = 0; kt < HOLD_KT; kt++) {
            half8 a = *(const half8*)&A[kt * 512 + ldsAoff];
            #pragma unroll
            for (int i = 0; i < NTW; i++)
                mfma_hv(acc[i], a, wreg[kt][i]);
        }

        // LDS-resident k-tiles
        #pragma unroll
        for (int kl = 0; kl < LDSB_KT; kl++) {
            half8 a = *(const half8*)&A[(LDSB_BASE + kl) * 512 + ldsAoff];
            #pragma unroll
            for (int i = 0; i < NTW; i++) {
                half8 b = *(const half8*)&BwL[kl * 16384 + bbL + i * 512];
                mfma_hv(acc[i], a, b);
            }
        }

        // streamed k-tiles with rolling 2-deep prefetch
        #pragma unroll
        for (int s = 0; s < STR_KT; s++) {
            const int kt = STR_BASE + s;
            half8 bpre[NTW];
            if (s + 2 < STR_KT) {
                #pragma unroll
                for (int i = 0; i < NTW; i++)
                    bpre[i] = *(const half8*)&Bw[bbase + (size_t)(kt + 2) * 16384 + i * 512];
            }
            half8 a = *(const half8*)&A[kt * 512 + ldsAoff];
            #pragma unroll
            for (int i = 0; i < NTW; i++)
                mfma_hv(acc[i], a, bcur[i]);
            #pragma unroll
            for (int i = 0; i < NTW; i++) {
                bcur[i] = bnxt[i];
                if (s + 2 < STR_KT) bnxt[i] = bpre[i];
            }
        }

        __syncthreads();   // all reads of A (h_t) complete before overwrite

        // ---- epilogue: combine hi/lo halves, tanh, write packed A in place ----
        float inp[4];
        if (enc) {
            #pragma unroll
            for (int r = 0; r < 4; r++) inp[r] = xs[mB + r][t];
        } else if (t == SEQ) {
            #pragma unroll
            for (int r = 0; r < 4; r++) inp[r] = xs[mB + r][SEQ - 1];
        } else {
            #pragma unroll
            for (int r = 0; r < 4; r++) inp[r] = dec_in_s[mB + r];
        }

        #pragma unroll
        for (int i = 0; i < NTW; i++) {
            int n = (wv * NTW + i) * 16 + c;   // this n is next step's k
            int G = (n >> 3) & 3;
            int base = (n >> 5) * 512 + G * 128 + (n & 7);
            float wi = enc ? eWi[i] : dWi[i];
            float bb = enc ? eBb[i] : dBb[i];
            #pragma unroll
            for (int r = 0; r < 4; r++) {
                // D rows 0-7 (lanes 0-31) = hi contribution, rows 8-15 (lanes 32-63) = lo
                float sum = acc[i][r] + __shfl_xor(acc[i][r], 32, 64);
                float v = ftanh(sum + inp[r] * wi + bb);
                _Float16 hh = (_Float16)v;
                _Float16 rs = (_Float16)(v - (float)hh);
                int mw = mB + r + (lohalf << 3);       // hi row or lo row
                A[base + ((mw ^ G) << 3)] = lohalf ? rs : hh;
            }
        }
        __syncthreads();   // A (h_{t+1}) complete

        if (!enc) {
            // FC: waves 0-7 each reduce one row; waves 8-15 idle to the barrier
            if (wv < 8) {
                const int m = wv;
                float sfc = 0.f;
                #pragma unroll
                for (int ii = 0; ii < HID / 64; ii++) {
                    int k = ii * 64 + lane;
                    int G = (k >> 3) & 3;
                    int a0 = (k >> 5) * 512 + G * 128 + (k & 7);
                    float hv = (float)A[a0 + ((m ^ G) << 3)]
                             + (float)A[a0 + (((m + 8) ^ G) << 3)];
                    sfc = fmaf(hv, fcW[k], sfc);
                }
                #pragma unroll
                for (int off = 32; off > 0; off >>= 1)
                    sfc += __shfl_down(sfc, off, 64);
                if (lane == 0) {
                    float o = sfc + fcb0;
                    dec_in_s[m] = o;
                    out[(size_t)(row0 + m) * OUTT + (t - SEQ)] = o;
                }
            }
            __syncthreads();
        }
    }
}

extern "C" void kernel_launch(void* const* d_in, const int* in_sizes, int n_in,
                              void* d_out, int out_size, void* d_ws, size_t ws_size,
                              hipStream_t stream)
{
    const float* x        = (const float*)d_in[0];
    const float* enc_Wih  = (const float*)d_in[1];
    const float* enc_Whh  = (const float*)d_in[2];
    const float* enc_bih  = (const float*)d_in[3];
    const float* enc_bhh  = (const float*)d_in[4];
    const float* dec_Wih  = (const float*)d_in[5];
    const float* dec_Whh  = (const float*)d_in[6];
    const float* dec_bih  = (const float*)d_in[7];
    const float* dec_bhh  = (const float*)d_in[8];
    const float* fc_W     = (const float*)d_in[9];
    const float* fc_b     = (const float*)d_in[10];
    float* out = (float*)d_out;

    const size_t wfrag = (size_t)HID * HID;
    _Float16* BwE = (_Float16*)d_ws;
    _Float16* BwD = BwE + wfrag;

    pack_wfrag<<<HID * HID / (256 * 8), 256, 0, stream>>>(enc_Whh, BwE);
    pack_wfrag<<<HID * HID / (256 * 8), 256, 0, stream>>>(dec_Whh, BwD);

    rnn_persist<<<NBLK, TPB, 0, stream>>>(
        x, BwE, BwD,
        enc_Wih, enc_bih, enc_bhh,
        dec_Wih, dec_bih, dec_bhh,
        fc_W, fc_b, out);
}